// Round 4
// baseline (127.668 us; speedup 1.0000x reference)
//
#include <hip/hip_runtime.h>
#include <math.h>

#define BB 4
#define NN 1024
#define DIN 128
#define DOUT 64
#define SLOPE 0.01f

// Kernel 1: wave-per-4-rows projection. Grid 1024, 64 thr/block (~16 WG/CU).
// Lane l owns output cols l (w1) and 64+l (w2) for 4 rows: 8 accumulators,
// each w-load amortized over 4 rows; unroll-4 keeps 8 loads in flight.
__global__ __launch_bounds__(64, 4) void proj_kernel(
    const float* __restrict__ x, const float* __restrict__ w1,
    const float* __restrict__ w2, float* __restrict__ x12) {
  int row0 = blockIdx.x * 4;
  int l = threadIdx.x;
  __shared__ __align__(16) float xl[4][DIN];  // 2 KB
  const float4* xg = reinterpret_cast<const float4*>(x + (size_t)row0 * DIN);
  float4* xs = reinterpret_cast<float4*>(&xl[0][0]);
  xs[l] = xg[l];
  xs[l + 64] = xg[l + 64];
  __syncthreads();
  const float* w1c = w1 + l;
  const float* w2c = w2 + l;
  float acc1[4] = {0.f, 0.f, 0.f, 0.f};
  float acc2[4] = {0.f, 0.f, 0.f, 0.f};
#pragma unroll 4
  for (int k = 0; k < DIN; ++k) {
    float wa = w1c[k * DOUT];  // coalesced 256B, L1/L2-hot
    float wb = w2c[k * DOUT];
#pragma unroll
    for (int r = 0; r < 4; ++r) {
      float xv = xl[r][k];  // LDS broadcast
      acc1[r] = fmaf(xv, wa, acc1[r]);
      acc2[r] = fmaf(xv, wb, acc2[r]);
    }
  }
#pragma unroll
  for (int r = 0; r < 4; ++r) {
    x12[(size_t)(row0 + r) * 128 + l] = acc1[r];
    x12[(size_t)(row0 + r) * 128 + DOUT + l] = acc2[r];
  }
}

__device__ __forceinline__ float fast_edge_exp(float sc) {
  // e = exp(8*tanh(sc/8)); tanh via exp, clamped so __expf stays finite
  float z = sc * 0.125f;
  z = fminf(10.f, fmaxf(-10.f, z));
  float u = __expf(2.f * z);
  float th = (u - 1.f) / (u + 1.f);
  return __expf(8.f * th);
}

// Kernel 2: ONE WAVE per (b,i) row; phase D software-pipelined 8 deep.
__global__ __launch_bounds__(64, 4) void gat_row_kernel(
    const float* __restrict__ x, const float* __restrict__ A_shape,
    const float* __restrict__ a_vec, const float* __restrict__ lin_w,
    const float* __restrict__ x12, float* __restrict__ out) {
  int bi = blockIdx.x;  // b*N + i
  int b = bi >> 10;
  int lane = threadIdx.x;

  __shared__ int eidx[NN + 8];                 // +8 pad slots
  __shared__ float evals[NN + 8];
  __shared__ __align__(16) float x1s[DOUT];
  __shared__ __align__(16) float avs[DOUT];
  __shared__ __align__(16) float agg[DIN];

  x1s[lane] = x12[(size_t)bi * 128 + lane];
  avs[lane] = a_vec[lane];

  // ---- Phase A: 16 independent coalesced mask loads, ballot-compact ----
  const float* mask_row = A_shape + (size_t)bi * NN;
  float mv[16];
#pragma unroll
  for (int c = 0; c < 16; ++c) mv[c] = mask_row[c * 64 + lane];
  int base = 0;
#pragma unroll
  for (int c = 0; c < 16; ++c) {
    bool pred = (mv[c] != 0.f);
    unsigned long long m = __ballot(pred);
    int prefix = __popcll(m & ((1ull << lane) - 1ull));
    if (pred) eidx[base + prefix] = c * 64 + lane;
    base += __popcll(m);  // wave-uniform
  }
  int nz = base;
  // pad to multiple of 8 with zero-weight self-edges (valid addresses)
  if (lane < 8) {
    eidx[nz + lane] = bi & (NN - 1);
    evals[nz + lane] = 0.f;
  }
  int nz8 = (nz + 7) & ~7;
  __syncthreads();

  // ---- Phase B: lane-per-edge scores (nz~51: one pass typical) ----
  const float* x2b = x12 + (size_t)b * NN * 128 + DOUT;  // x2 half, stride 128
  float lsum = 0.f;
  for (int s = lane; s < nz; s += 64) {
    const float* x2r = x2b + (size_t)eidx[s] * 128;
    float sc = 0.f;
#pragma unroll
    for (int d0 = 0; d0 < DOUT; d0 += 4) {
      float4 x2v = *reinterpret_cast<const float4*>(x2r + d0);
      float4 x1v = *reinterpret_cast<const float4*>(&x1s[d0]);
      float4 avv = *reinterpret_cast<const float4*>(&avs[d0]);
      float z;
      z = x1v.x + x2v.x; sc = fmaf(z >= 0.f ? z : SLOPE * z, avv.x, sc);
      z = x1v.y + x2v.y; sc = fmaf(z >= 0.f ? z : SLOPE * z, avv.y, sc);
      z = x1v.z + x2v.z; sc = fmaf(z >= 0.f ? z : SLOPE * z, avv.z, sc);
      z = x1v.w + x2v.w; sc = fmaf(z >= 0.f ? z : SLOPE * z, avv.w, sc);
    }
    float e = fast_edge_exp(sc);
    evals[s] = e;
    lsum += e;
  }

  // ---- Phase C: wave-reduce row sum ----
#pragma unroll
  for (int off = 32; off > 0; off >>= 1) lsum += __shfl_xor(lsum, off, 64);
  float inv = 1.f / lsum;
  __syncthreads();

  // ---- Phase D: agg[k] = inv * sum_s evals[s]*x[b,eidx[s],k]
  //      lane owns k={2*lane, 2*lane+1}; 8 edges batched: 8 independent
  //      coalesced 512B row-gathers in flight per batch, no serial tail ----
  const float* xb = x + (size_t)b * NN * DIN;
  float ax0 = 0.f, ay0 = 0.f, ax1 = 0.f, ay1 = 0.f;
  for (int s = 0; s < nz8; s += 8) {
    int j[8];
    float w[8];
#pragma unroll
    for (int r = 0; r < 8; ++r) { j[r] = eidx[s + r]; w[r] = evals[s + r]; }
    float2 xv[8];
#pragma unroll
    for (int r = 0; r < 8; ++r)
      xv[r] = *reinterpret_cast<const float2*>(xb + (size_t)j[r] * 128 + lane * 2);
#pragma unroll
    for (int r = 0; r < 8; r += 2) {
      ax0 = fmaf(w[r], xv[r].x, ax0);
      ay0 = fmaf(w[r], xv[r].y, ay0);
      ax1 = fmaf(w[r + 1], xv[r + 1].x, ax1);
      ay1 = fmaf(w[r + 1], xv[r + 1].y, ay1);
    }
  }
  float2 ag2 = {(ax0 + ax1) * inv, (ay0 + ay1) * inv};
  reinterpret_cast<float2*>(agg)[lane] = ag2;
  __syncthreads();

  // ---- Phase E: out[d] = lrelu(sum_k agg[k]*lin_w[d,k]), lane = d ----
  const float* lw = lin_w + (size_t)lane * DIN;
  float o = 0.f;
#pragma unroll
  for (int k = 0; k < DIN; k += 4) {
    float4 lv = *reinterpret_cast<const float4*>(lw + k);
    float4 ag = *reinterpret_cast<const float4*>(&agg[k]);
    o = fmaf(ag.x, lv.x, o);
    o = fmaf(ag.y, lv.y, o);
    o = fmaf(ag.z, lv.z, o);
    o = fmaf(ag.w, lv.w, o);
  }
  o = o >= 0.f ? o : SLOPE * o;
  out[(size_t)bi * DOUT + lane] = o;
}

extern "C" void kernel_launch(void* const* d_in, const int* in_sizes, int n_in,
                              void* d_out, int out_size, void* d_ws, size_t ws_size,
                              hipStream_t stream) {
  const float* x = (const float*)d_in[0];
  const float* A_shape = (const float*)d_in[1];
  const float* w1 = (const float*)d_in[2];
  const float* w2 = (const float*)d_in[3];
  const float* a = (const float*)d_in[4];
  const float* lin_w = (const float*)d_in[5];
  float* out = (float*)d_out;
  float* x12 = (float*)d_ws;  // B*N*128 floats = 2 MB scratch

  proj_kernel<<<BB * NN / 4, 64, 0, stream>>>(x, w1, w2, x12);
  gat_row_kernel<<<BB * NN, 64, 0, stream>>>(x, A_shape, a, lin_w, x12, out);
}

// Round 5
// 110.364 us; speedup vs baseline: 1.1568x; 1.1568x over previous
//
#include <hip/hip_runtime.h>
#include <math.h>

#define BB 4
#define NN 1024
#define DIN 128
#define DOUT 64
#define SLOPE 0.01f

// ws layout: [0, 2 MB) = x12 (B*N*128 fp32); [2 MB, 2 MB+32 KB) = lwT[128][64]

// Kernel 1: wave-per-4-rows projection (grid 1024) + one extra block (1024)
// that transposes lin_w [64][128] -> lwT [128][64] so kernel 2's epilogue
// can read it coalesced.
__global__ __launch_bounds__(64, 4) void proj_kernel(
    const float* __restrict__ x, const float* __restrict__ w1,
    const float* __restrict__ w2, const float* __restrict__ lin_w,
    float* __restrict__ x12, float* __restrict__ lwT) {
  int l = threadIdx.x;
  if (blockIdx.x == BB * NN / 4) {
    // tiny: 8192 elements, one wave
    for (int idx = l; idx < DOUT * DIN; idx += 64) {
      int k = idx >> 6, d = idx & 63;
      lwT[idx] = lin_w[d * DIN + k];
    }
    return;
  }
  int row0 = blockIdx.x * 4;
  __shared__ __align__(16) float xl[4][DIN];  // 2 KB
  const float4* xg = reinterpret_cast<const float4*>(x + (size_t)row0 * DIN);
  float4* xs = reinterpret_cast<float4*>(&xl[0][0]);
  xs[l] = xg[l];
  xs[l + 64] = xg[l + 64];
  __syncthreads();
  const float* w1c = w1 + l;
  const float* w2c = w2 + l;
  float acc1[4] = {0.f, 0.f, 0.f, 0.f};
  float acc2[4] = {0.f, 0.f, 0.f, 0.f};
#pragma unroll 4
  for (int k = 0; k < DIN; ++k) {
    float wa = w1c[k * DOUT];  // coalesced 256B
    float wb = w2c[k * DOUT];
#pragma unroll
    for (int r = 0; r < 4; ++r) {
      float xv = xl[r][k];  // LDS broadcast
      acc1[r] = fmaf(xv, wa, acc1[r]);
      acc2[r] = fmaf(xv, wb, acc2[r]);
    }
  }
#pragma unroll
  for (int r = 0; r < 4; ++r) {
    x12[(size_t)(row0 + r) * 128 + l] = acc1[r];
    x12[(size_t)(row0 + r) * 128 + DOUT + l] = acc2[r];
  }
}

__device__ __forceinline__ float fast_edge_exp(float sc) {
  // e = exp(8*tanh(sc/8)); tanh via exp, clamped so __expf stays finite
  float z = sc * 0.125f;
  z = fminf(10.f, fmaxf(-10.f, z));
  float u = __expf(2.f * z);
  float th = (u - 1.f) / (u + 1.f);
  return __expf(8.f * th);
}

// Kernel 2: ONE WAVE per (b,i) row. All global accesses coalesced:
//  A: 16x 256B mask loads, ballot-compact.
//  B: 16 lanes per edge (4 edges per instr, 16 full lines/instr).
//  D: lane owns k-pair; 8 independent 512B row-gathers per batch.
//  E: lwT[k][d] read coalesced (L1-hot), agg via LDS broadcast.
__global__ __launch_bounds__(64, 4) void gat_row_kernel(
    const float* __restrict__ x, const float* __restrict__ A_shape,
    const float* __restrict__ a_vec, const float* __restrict__ lwT,
    const float* __restrict__ x12, float* __restrict__ out) {
  int bi = blockIdx.x;  // b*N + i
  int b = bi >> 10;
  int lane = threadIdx.x;

  __shared__ int eidx[NN + 8];
  __shared__ float evals[NN + 8];
  __shared__ __align__(16) float x1s[DOUT];
  __shared__ __align__(16) float avs[DOUT];
  __shared__ __align__(16) float agg[DIN];

  x1s[lane] = x12[(size_t)bi * 128 + lane];
  avs[lane] = a_vec[lane];

  // ---- Phase A: coalesced mask loads + ballot compact ----
  const float* mask_row = A_shape + (size_t)bi * NN;
  float mv[16];
#pragma unroll
  for (int c = 0; c < 16; ++c) mv[c] = mask_row[c * 64 + lane];
  int base = 0;
#pragma unroll
  for (int c = 0; c < 16; ++c) {
    bool pred = (mv[c] != 0.f);
    unsigned long long m = __ballot(pred);
    int prefix = __popcll(m & ((1ull << lane) - 1ull));
    if (pred) eidx[base + prefix] = c * 64 + lane;
    base += __popcll(m);  // wave-uniform
  }
  int nz = base;
  int nz8 = (nz + 7) & ~7;
  if (lane < 8) {               // zero-weight pad edges (valid addresses)
    eidx[nz + lane] = bi & (NN - 1);
    evals[nz + lane] = 0.f;
  }
  __syncthreads();

  // ---- Phase B: 16-lane groups, 4 edges in parallel, coalesced ----
  const float* x2b = x12 + (size_t)b * NN * 128 + DOUT;  // x2 half, stride 128
  int l16 = lane & 15;
  int grp = lane >> 4;
  float4 x1v = reinterpret_cast<const float4*>(x1s)[l16];
  float4 avv = reinterpret_cast<const float4*>(avs)[l16];
  float lsum = 0.f;
  for (int s = grp; s < nz8; s += 4) {
    int j = eidx[s];  // 4 distinct addrs per wave (per-group broadcast)
    float4 x2v = *reinterpret_cast<const float4*>(
        x2b + (size_t)j * 128 + l16 * 4);  // 4 groups x 256B = 16 lines/instr
    float z, sc = 0.f;
    z = x1v.x + x2v.x; sc = fmaf(z >= 0.f ? z : SLOPE * z, avv.x, sc);
    z = x1v.y + x2v.y; sc = fmaf(z >= 0.f ? z : SLOPE * z, avv.y, sc);
    z = x1v.z + x2v.z; sc = fmaf(z >= 0.f ? z : SLOPE * z, avv.z, sc);
    z = x1v.w + x2v.w; sc = fmaf(z >= 0.f ? z : SLOPE * z, avv.w, sc);
    sc += __shfl_xor(sc, 8, 16);
    sc += __shfl_xor(sc, 4, 16);
    sc += __shfl_xor(sc, 2, 16);
    sc += __shfl_xor(sc, 1, 16);
    if (l16 == 0 && s < nz) {
      float e = fast_edge_exp(sc);
      evals[s] = e;
      lsum += e;
    }
  }

  // ---- Phase C: wave-reduce row sum (non-leaders hold 0) ----
#pragma unroll
  for (int off = 32; off > 0; off >>= 1) lsum += __shfl_xor(lsum, off, 64);
  float inv = 1.f / lsum;
  __syncthreads();

  // ---- Phase D: lane owns k-pair; 8 coalesced row-gathers in flight ----
  const float* xb = x + (size_t)b * NN * DIN;
  float ax0 = 0.f, ay0 = 0.f, ax1 = 0.f, ay1 = 0.f;
  for (int s = 0; s < nz8; s += 8) {
    int j[8];
    float w[8];
#pragma unroll
    for (int r = 0; r < 8; ++r) { j[r] = eidx[s + r]; w[r] = evals[s + r]; }
    float2 xv[8];
#pragma unroll
    for (int r = 0; r < 8; ++r)
      xv[r] = *reinterpret_cast<const float2*>(xb + (size_t)j[r] * 128 + lane * 2);
#pragma unroll
    for (int r = 0; r < 8; r += 2) {
      ax0 = fmaf(w[r], xv[r].x, ax0);
      ay0 = fmaf(w[r], xv[r].y, ay0);
      ax1 = fmaf(w[r + 1], xv[r + 1].x, ax1);
      ay1 = fmaf(w[r + 1], xv[r + 1].y, ay1);
    }
  }
  float2 ag2 = {(ax0 + ax1) * inv, (ay0 + ay1) * inv};
  reinterpret_cast<float2*>(agg)[lane] = ag2;
  __syncthreads();

  // ---- Phase E: out[d] = lrelu(sum_k agg[k]*lwT[k][d]), coalesced lwT ----
  float o = 0.f;
#pragma unroll 8
  for (int k = 0; k < DIN; ++k) {
    // agg[k]: LDS broadcast; lwT: 256B coalesced, L1-hot (32 KB shared)
    o = fmaf(agg[k], lwT[k * DOUT + lane], o);
  }
  o = o >= 0.f ? o : SLOPE * o;
  out[(size_t)bi * DOUT + lane] = o;
}

extern "C" void kernel_launch(void* const* d_in, const int* in_sizes, int n_in,
                              void* d_out, int out_size, void* d_ws, size_t ws_size,
                              hipStream_t stream) {
  const float* x = (const float*)d_in[0];
  const float* A_shape = (const float*)d_in[1];
  const float* w1 = (const float*)d_in[2];
  const float* w2 = (const float*)d_in[3];
  const float* a = (const float*)d_in[4];
  const float* lin_w = (const float*)d_in[5];
  float* out = (float*)d_out;
  float* x12 = (float*)d_ws;                       // 2 MB
  float* lwT = (float*)d_ws + (size_t)BB * NN * 128;  // 32 KB

  proj_kernel<<<BB * NN / 4 + 1, 64, 0, stream>>>(x, w1, w2, lin_w, x12, lwT);
  gat_row_kernel<<<BB * NN, 64, 0, stream>>>(x, A_shape, a, lwT, x12, out);
}

// Round 6
// 101.057 us; speedup vs baseline: 1.2633x; 1.0921x over previous
//
#include <hip/hip_runtime.h>
#include <math.h>

#define BB 4
#define NN 1024
#define DIN 128
#define DOUT 64
#define SLOPE 0.01f

// ws layout: [0, 2 MB) = x12 (B*N*128 fp32); then lwT[128][64] (32 KB)

// Kernel 1: wave-per-row projection, grid 4096 rows + 8 transpose blocks.
// 16 waves/CU; k-loop unroll 8 keeps 16 independent L1-hot loads in flight.
__global__ __launch_bounds__(64, 8) void proj_kernel(
    const float* __restrict__ x, const float* __restrict__ w1,
    const float* __restrict__ w2, const float* __restrict__ lin_w,
    float* __restrict__ x12, float* __restrict__ lwT) {
  int l = threadIdx.x;
  if (blockIdx.x >= BB * NN) {
    // transpose lin_w [64][128] -> lwT [128][64]; 8 blocks x 1024 elems
    int base = (blockIdx.x - BB * NN) * 1024;
#pragma unroll
    for (int i = 0; i < 16; ++i) {
      int idx = base + i * 64 + l;        // flat over lin_w [d][k]
      int d = idx >> 7, k = idx & 127;
      lwT[k * DOUT + d] = lin_w[idx];     // coalesced read, scattered write
    }
    return;
  }
  int row = blockIdx.x;
  __shared__ __align__(16) float xl[DIN];
  reinterpret_cast<float2*>(xl)[l] =
      reinterpret_cast<const float2*>(x + (size_t)row * DIN)[l];
  __syncthreads();
  const float* w1c = w1 + l;
  const float* w2c = w2 + l;
  float a1 = 0.f, a2 = 0.f;
#pragma unroll 8
  for (int k = 0; k < DIN; ++k) {
    float xv = xl[k];                     // LDS broadcast
    a1 = fmaf(xv, w1c[k * DOUT], a1);     // coalesced 256B, L1-hot
    a2 = fmaf(xv, w2c[k * DOUT], a2);
  }
  x12[(size_t)row * 128 + l] = a1;
  x12[(size_t)row * 128 + DOUT + l] = a2;
}

__device__ __forceinline__ float fast_edge_exp(float sc) {
  // e = exp(8*tanh(sc/8)); tanh via exp, clamped so __expf stays finite
  float z = sc * 0.125f;
  z = fminf(10.f, fmaxf(-10.f, z));
  float u = __expf(2.f * z);
  float th = (u - 1.f) / (u + 1.f);
  return __expf(8.f * th);
}

// Kernel 2: TWO WAVES per (b,i) row (128 thr), grid 4096 -> 32 waves/CU.
// Wave w compacts mask columns [512w, 512w+512); edge list is two segments
// (seg0 at 0, seg1 at 512); phys(s) = s<nz0 ? s : 512+s-nz0.
__global__ __launch_bounds__(128, 8) void gat_row_kernel(
    const float* __restrict__ x, const float* __restrict__ A_shape,
    const float* __restrict__ a_vec, const float* __restrict__ lwT,
    const float* __restrict__ x12, float* __restrict__ out) {
  int bi = blockIdx.x;  // b*N + i
  int b = bi >> 10;
  int tid = threadIdx.x;
  int lane = tid & 63;
  int w = tid >> 6;

  __shared__ int eidx[1032];                  // seg0:[0,512) seg1:[512,1032)
  __shared__ float evals[1032];
  __shared__ __align__(16) float x1s[DOUT];
  __shared__ __align__(16) float avs[DOUT];
  __shared__ __align__(16) float agg[DIN];
  __shared__ float ep[2][DOUT];
  __shared__ float wsum[2];
  __shared__ int cnt[2];

  if (tid < DOUT) {
    x1s[tid] = x12[(size_t)bi * 128 + tid];
    avs[tid] = a_vec[tid];
  }

  // ---- Phase A: each wave compacts its 512 mask columns ----
  const float* mask_row = A_shape + (size_t)bi * NN + w * 512;
  float mv[8];
#pragma unroll
  for (int c = 0; c < 8; ++c) mv[c] = mask_row[c * 64 + lane];
  int base = 0;
  int seg = w * 512;
#pragma unroll
  for (int c = 0; c < 8; ++c) {
    bool pred = (mv[c] != 0.f);
    unsigned long long m = __ballot(pred);
    int prefix = __popcll(m & ((1ull << lane) - 1ull));
    if (pred) eidx[seg + base + prefix] = w * 512 + c * 64 + lane;
    base += __popcll(m);  // wave-uniform
  }
  if (lane == 0) cnt[w] = base;
  __syncthreads();

  int nz0 = cnt[0], nz1 = cnt[1];
  int nzt = nz0 + nz1;
  int nzt8 = (nzt + 7) & ~7;
  if (tid < 8) {  // zero-weight pad edges after seg1 (capacity 512+8)
    eidx[512 + nz1 + tid] = bi & (NN - 1);
    evals[512 + nz1 + tid] = 0.f;
  }
  __syncthreads();

  // ---- Phase B: 8 groups x 16 lanes, 8 edges per iteration ----
  const float* x2b = x12 + (size_t)b * NN * 128 + DOUT;  // x2 half, stride 128
  int l16 = tid & 15;
  int grp = tid >> 4;
  float4 x1v = reinterpret_cast<const float4*>(x1s)[l16];
  float4 avv = reinterpret_cast<const float4*>(avs)[l16];
  float lsum = 0.f;
  for (int s = grp; s < nzt8; s += 8) {
    int ps = (s < nz0) ? s : 512 + s - nz0;
    int j = eidx[ps];
    float4 x2v = *reinterpret_cast<const float4*>(
        x2b + (size_t)j * 128 + l16 * 4);  // 8 groups x 256B coalesced
    float z, sc = 0.f;
    z = x1v.x + x2v.x; sc = fmaf(z >= 0.f ? z : SLOPE * z, avv.x, sc);
    z = x1v.y + x2v.y; sc = fmaf(z >= 0.f ? z : SLOPE * z, avv.y, sc);
    z = x1v.z + x2v.z; sc = fmaf(z >= 0.f ? z : SLOPE * z, avv.z, sc);
    z = x1v.w + x2v.w; sc = fmaf(z >= 0.f ? z : SLOPE * z, avv.w, sc);
    sc += __shfl_xor(sc, 8, 16);
    sc += __shfl_xor(sc, 4, 16);
    sc += __shfl_xor(sc, 2, 16);
    sc += __shfl_xor(sc, 1, 16);
    if (l16 == 0 && s < nzt) {
      float e = fast_edge_exp(sc);
      evals[ps] = e;
      lsum += e;
    }
  }

  // ---- Phase C: block-reduce row sum (leaders hold partials) ----
#pragma unroll
  for (int off = 32; off > 0; off >>= 1) lsum += __shfl_xor(lsum, off, 64);
  if (lane == 0) wsum[w] = lsum;
  __syncthreads();
  float inv = 1.f / (wsum[0] + wsum[1]);

  // ---- Phase D: thread owns k=tid; 8 coalesced 512B row-gathers/batch ----
  const float* xk = x + (size_t)b * NN * DIN + tid;
  float acc0 = 0.f, acc1 = 0.f;
  for (int s = 0; s < nzt8; s += 8) {
    int j[8];
    float wt[8];
#pragma unroll
    for (int r = 0; r < 8; ++r) {
      int ss = s + r;
      int ps = (ss < nz0) ? ss : 512 + ss - nz0;
      j[r] = eidx[ps];   // LDS broadcast (same across block)
      wt[r] = evals[ps];
    }
    float xv[8];
#pragma unroll
    for (int r = 0; r < 8; ++r) xv[r] = xk[(size_t)j[r] * 128];
#pragma unroll
    for (int r = 0; r < 8; r += 2) {
      acc0 = fmaf(wt[r], xv[r], acc0);
      acc1 = fmaf(wt[r + 1], xv[r + 1], acc1);
    }
  }
  agg[tid] = (acc0 + acc1) * inv;
  __syncthreads();

  // ---- Phase E: thread = (d, k-half); coalesced L1-hot lwT reads ----
  int d = tid & 63;
  int h = tid >> 6;
  const float* lwc = lwT + (size_t)h * 64 * DOUT + d;
  const float* agh = agg + h * 64;
  float o = 0.f;
#pragma unroll 8
  for (int k = 0; k < 64; ++k)
    o = fmaf(agh[k], lwc[k * DOUT], o);
  ep[h][d] = o;
  __syncthreads();
  if (tid < DOUT) {
    float oo = ep[0][tid] + ep[1][tid];
    oo = oo >= 0.f ? oo : SLOPE * oo;
    out[(size_t)bi * DOUT + tid] = oo;
  }
}

extern "C" void kernel_launch(void* const* d_in, const int* in_sizes, int n_in,
                              void* d_out, int out_size, void* d_ws, size_t ws_size,
                              hipStream_t stream) {
  const float* x = (const float*)d_in[0];
  const float* A_shape = (const float*)d_in[1];
  const float* w1 = (const float*)d_in[2];
  const float* w2 = (const float*)d_in[3];
  const float* a = (const float*)d_in[4];
  const float* lin_w = (const float*)d_in[5];
  float* out = (float*)d_out;
  float* x12 = (float*)d_ws;                          // 2 MB
  float* lwT = (float*)d_ws + (size_t)BB * NN * 128;  // 32 KB

  proj_kernel<<<BB * NN + 8, 64, 0, stream>>>(x, w1, w2, lin_w, x12, lwT);
  gat_row_kernel<<<BB * NN, 128, 0, stream>>>(x, A_shape, a, lwT, x12, out);
}